// Round 5
// baseline (243.718 us; speedup 1.0000x reference)
//
#include <hip/hip_runtime.h>

// Problem constants (from reference)
#define BS    4
#define CH    64
#define HH    32
#define WW    88
#define NZ    60
#define BEV_Z 10
#define BEV_X 128
#define BEV_Y 128

static constexpr int HW        = HH * WW;        // 2816
static constexpr int ZX        = BEV_Z * BEV_X;  // 1280 output cells per (b,ch)
static constexpr int PTS_PER_B = NZ * HW;        // 168960

static constexpr int NSEG    = 32;                    // point segments per batch
static constexpr int SEG_PTS = PTS_PER_B / NSEG;      // 5280 (exact)
static constexpr int CCH     = 16;                    // channels per chunk
static constexpr int NCC     = CH / CCH;              // 4
static constexpr int TILE_W  = CCH * ZX;              // 20480 words = 80 KB LDS
                                                      // (no pad: lanes in one DS op share ch,
                                                      //  so bank = zx%32 is already spread)

// K1: block = (seg, b, cc). Accumulate partial BEV tile in LDS, dump to P.
// P layout: [seg][b][cc][CCH][ZX]  (41.9 MB in d_ws)
__global__ __launch_bounds__(256)
void accum_kernel(const float* __restrict__ x, const int* __restrict__ f,
                  float* __restrict__ P) {
    __shared__ float tile[TILE_W];
    int blk = blockIdx.x;
    int cc  = blk % NCC;
    int b   = (blk / NCC) % BS;
    int seg = blk / (NCC * BS);

    for (int i = threadIdx.x; i < TILE_W; i += 256) tile[i] = 0.f;
    __syncthreads();

    const float* xb = x + ((size_t)b * CH + cc * CCH) * HW;
    int rel0 = seg * SEG_PTS;                 // point offset within batch b
    int p0   = b * PTS_PER_B + rel0;

    for (int i = threadIdx.x; i < SEG_PTS; i += 256) {
        int p  = p0 + i;
        int xx = f[3 * p + 0];
        int yy = f[3 * p + 1];
        int zz = f[3 * p + 2];
        bool kept = (xx >= 0) & (xx < BEV_X) & (yy >= 0) & (yy < BEV_Y) &
                    (zz >= 0) & (zz < BEV_Z);
        if (!kept) continue;
        int hw = (rel0 + i) % HW;             // rel = nz*HW + hw
        int zx = zz * BEV_X + xx;
        #pragma unroll
        for (int c = 0; c < CCH; ++c) {
            atomicAdd(&tile[c * ZX + zx], xb[c * HW + hw]);   // ds_add_f32
        }
    }
    __syncthreads();

    float* Pb = P + (size_t)blk * TILE_W;     // blk == ((seg*BS+b)*NCC+cc)
    for (int i = threadIdx.x; i < TILE_W; i += 256) Pb[i] = tile[i];
}

// K2: out[b][ch][zx] = sum over seg of P[seg][b][cc][cl][zx]
__global__ __launch_bounds__(256)
void reduce_kernel(const float* __restrict__ P, float* __restrict__ out) {
    int idx = blockIdx.x * 256 + threadIdx.x;     // 0 .. BS*CH*ZX-1 (327680)
    int zx = idx % ZX;
    int ch = (idx / ZX) % CH;
    int b  = idx / (ZX * CH);
    int cc = ch / CCH;
    int cl = ch % CCH;

    const float* p = P + (((size_t)b * NCC + cc) * CCH + cl) * ZX + zx;
    constexpr size_t SEG_STRIDE = (size_t)BS * NCC * CCH * ZX;   // 327680 floats
    float s = 0.f;
    #pragma unroll
    for (int seg = 0; seg < NSEG; ++seg)
        s += p[seg * SEG_STRIDE];
    out[idx] = s;
}

extern "C" void kernel_launch(void* const* d_in, const int* in_sizes, int n_in,
                              void* d_out, int out_size, void* d_ws, size_t ws_size,
                              hipStream_t stream) {
    const float* x = (const float*)d_in[0];
    const int*   f = (const int*)d_in[1];
    float*       out = (float*)d_out;
    float*       P   = (float*)d_ws;   // 32*4*4*16*1280*4 B = 41.9 MB, fully
                                       // written by K1 before K2 reads it

    accum_kernel <<<NSEG * BS * NCC, 256, 0, stream>>>(x, f, P);
    reduce_kernel<<<(BS * CH * ZX) / 256, 256, 0, stream>>>(P, out);
}

// Round 6
// 112.226 us; speedup vs baseline: 2.1717x; 2.1717x over previous
//
#include <hip/hip_runtime.h>
#include <hip/hip_bf16.h>

// Problem constants (from reference)
#define BS    4
#define CH    64
#define HH    32
#define WW    88
#define NZ    60
#define BEV_Z 10
#define BEV_X 128
#define BEV_Y 128

static constexpr int HW        = HH * WW;        // 2816
static constexpr int ZX        = BEV_Z * BEV_X;  // 1280
static constexpr int PTS_PER_B = NZ * HW;        // 168960

static constexpr int T          = 16;            // hw columns per count tile
static constexpr int NT         = HW / T;        // 176 tiles per batch
static constexpr int CNT_BLOCKS = BS * NT;       // 704
static constexpr int NXELEM     = BS * CH * HW;  // 720896
static constexpr int XCONV_BLOCKS = NXELEM / 4096; // 176 (4096 elems/block)
static constexpr int CNT_WORDS  = ZX * T / 4;    // 5120 u32 (u8-packed counts)

typedef __attribute__((ext_vector_type(8))) short short8;   // bf16x8 MFMA frag
typedef __attribute__((ext_vector_type(4))) float floatx4;  // fp32x4 acc

__device__ inline unsigned short f2b(float v) {
    __hip_bfloat16 h = __float2bfloat16(v);
    return *reinterpret_cast<unsigned short*>(&h);
}

// ---- K1: blocks 0..703 build cnt (bf16), blocks 704..879 cast x -> bf16 ----
__global__ __launch_bounds__(256)
void build_kernel(const float* __restrict__ x, const int* __restrict__ f,
                  unsigned short* __restrict__ cntbf,
                  unsigned short* __restrict__ xbf) {
    __shared__ unsigned int cnt[CNT_WORDS];   // [zx][hw_l] u8-packed, 20 KB
    int blk = blockIdx.x;
    if (blk < CNT_BLOCKS) {
        int b   = blk / NT;
        int hw0 = (blk % NT) * T;
        for (int i = threadIdx.x; i < CNT_WORDS; i += 256) cnt[i] = 0u;
        __syncthreads();

        int hw_l = threadIdx.x & 15;
        int z0   = threadIdx.x >> 4;          // 16 z-rows per pass
        for (int z = z0; z < NZ; z += 16) {
            int p  = b * PTS_PER_B + z * HW + hw0 + hw_l;
            int xx = f[3 * p + 0];
            int yy = f[3 * p + 1];
            int zz = f[3 * p + 2];
            bool kept = (xx >= 0) & (xx < BEV_X) & (yy >= 0) & (yy < BEV_Y) &
                        (zz >= 0) & (zz < BEV_Z);
            if (kept) {
                int zx   = zz * BEV_X + xx;
                int cell = zx * T + hw_l;     // counts <= 60: no u8 overflow
                atomicAdd(&cnt[cell >> 2], 1u << (8 * (cell & 3)));
            }
        }
        __syncthreads();

        // write tile as bf16 (exact for small ints)
        for (int i = threadIdx.x; i < CNT_WORDS; i += 256) {
            unsigned int wv = cnt[i];
            int zx = i >> 2, q = i & 3;
            ushort4 o;
            o.x = f2b((float)( wv        & 255u));
            o.y = f2b((float)((wv >>  8) & 255u));
            o.z = f2b((float)((wv >> 16) & 255u));
            o.w = f2b((float)((wv >> 24) & 255u));
            *(ushort4*)(cntbf + ((size_t)(b * ZX + zx)) * HW + hw0 + q * 4) = o;
        }
    } else {
        // cast x (b,ch,hw) fp32 -> bf16, same layout
        size_t base = (size_t)(blk - CNT_BLOCKS) * 4096;
        #pragma unroll
        for (int r = 0; r < 4; ++r) {
            size_t i = base + ((size_t)r * 256 + threadIdx.x) * 4;
            floatx4 v = *(const floatx4*)(x + i);
            ushort4 o;
            o.x = f2b(v.x); o.y = f2b(v.y); o.z = f2b(v.z); o.w = f2b(v.w);
            *(ushort4*)(xbf + i) = o;
        }
    }
}

// ---- K2: out[b] (64x1280) = xbf[b] (64x2816) * cntbf[b]^T (2816x1280) ----
// Block = (b, 16-wide zx tile); wave = 16-ch tile; MFMA 16x16x32 bf16.
// A frag: lane holds A[m=lane&15][k=quad*8+j] -> 16B contiguous in hw.
// B frag: lane holds B[k=quad*8+j][n=lane&15] = cnt[zx=n][hw=k] -> 16B contiguous.
// D frag: col(zx)=lane&15, row(ch)=quad*4+reg  [measured m89]
__global__ __launch_bounds__(256)
void gemm_kernel(const unsigned short* __restrict__ xbf,
                 const unsigned short* __restrict__ cntbf,
                 float* __restrict__ out) {
    int blk  = blockIdx.x;                 // 0..319
    int b    = blk / (ZX / 16);
    int zx0  = (blk % (ZX / 16)) * 16;
    int wave = threadIdx.x >> 6;
    int lane = threadIdx.x & 63;
    int ch0  = wave * 16;

    int m    = lane & 15;
    int quad = lane >> 4;

    const unsigned short* pa = xbf   + ((size_t)(b * CH + ch0 + m)) * HW + quad * 8;
    const unsigned short* pb = cntbf + ((size_t)(b * ZX + zx0 + m)) * HW + quad * 8;

    floatx4 acc = {0.f, 0.f, 0.f, 0.f};
    for (int k = 0; k < HW; k += 128) {    // 22 iters, 4 MFMA each
        short8 a0 = *(const short8*)(pa + k);
        short8 b0 = *(const short8*)(pb + k);
        short8 a1 = *(const short8*)(pa + k + 32);
        short8 b1 = *(const short8*)(pb + k + 32);
        short8 a2 = *(const short8*)(pa + k + 64);
        short8 b2 = *(const short8*)(pb + k + 64);
        short8 a3 = *(const short8*)(pa + k + 96);
        short8 b3 = *(const short8*)(pb + k + 96);
        acc = __builtin_amdgcn_mfma_f32_16x16x32_bf16(a0, b0, acc, 0, 0, 0);
        acc = __builtin_amdgcn_mfma_f32_16x16x32_bf16(a1, b1, acc, 0, 0, 0);
        acc = __builtin_amdgcn_mfma_f32_16x16x32_bf16(a2, b2, acc, 0, 0, 0);
        acc = __builtin_amdgcn_mfma_f32_16x16x32_bf16(a3, b3, acc, 0, 0, 0);
    }

    int zx = zx0 + m;
    #pragma unroll
    for (int r = 0; r < 4; ++r) {
        int ch = ch0 + quad * 4 + r;
        out[((size_t)(b * CH + ch)) * ZX + zx] = acc[r];
    }
}

extern "C" void kernel_launch(void* const* d_in, const int* in_sizes, int n_in,
                              void* d_out, int out_size, void* d_ws, size_t ws_size,
                              hipStream_t stream) {
    const float* x = (const float*)d_in[0];
    const int*   f = (const int*)d_in[1];
    float*       out = (float*)d_out;

    char* ws = (char*)d_ws;
    size_t off = 0;
    auto carve = [&](size_t bytes) {
        char* p = ws + off;
        off += (bytes + 255) & ~(size_t)255;
        return p;
    };
    unsigned short* cntbf = (unsigned short*)carve((size_t)BS * ZX * HW * 2); // 28.8 MB
    unsigned short* xbf   = (unsigned short*)carve((size_t)NXELEM * 2);       // 1.44 MB
    // both fully written by K1 before K2 reads them -> no memset needed

    build_kernel<<<CNT_BLOCKS + XCONV_BLOCKS, 256, 0, stream>>>(x, f, cntbf, xbf);
    gemm_kernel <<<BS * (ZX / 16), 256, 0, stream>>>(xbf, cntbf, out);
}